// Round 8
// baseline (200.257 us; speedup 1.0000x reference)
//
#include <hip/hip_runtime.h>
#include <hip/hip_bf16.h>

#define CIN   256
#define COUT  256
#define HH    56
#define WW    56
#define NB    32
#define KTOT  2304            // 3*3*256
#define MTOT  (NB * HH * WW)  // 100352

// ---- geometry (R2-proven): 128x256 tile, 8 waves (64x64 each), BK=64,
//      single-buffered LDS, 2 barriers/step.  Round-8: T14 reg-prefetch
//      (issue next tile's global loads under compute), no xcast pre-pass. ----
#define BM 128
#define BN 256
#define BK 64
#define NTHREADS 512
#define NSTEPS (KTOT / BK)    // 36 = 4 cin-chunks(64) * 9 taps

typedef __attribute__((ext_vector_type(4))) float  f32x4;
typedef __attribute__((ext_vector_type(8))) __bf16 bf16x8;

// ---- binarize W -> bt[cout][ks*64 + swz(ci)] bf16 {+-1,0}; BK=64 layout ----
// ks = cin_chunk64 * 9 + tap (taps innermost). Pre-swizzle: ci ^ ((co&7)<<3).
// (R2-proven layout: 0 LDS bank conflicts)
__global__ void binarize_w_kernel(const float* __restrict__ W,
                                  unsigned short* __restrict__ bt) {
    int k  = blockIdx.x;    // tap*256 + cin
    int co = threadIdx.x;
    int tap = k >> 8, cin = k & 255;
    int c = cin >> 6, ci = cin & 63;
    int ks = c * 9 + tap;
    float w = W[(size_t)k * COUT + co];
    unsigned short s = (w > 0.f) ? 0x3F80u : ((w < 0.f) ? 0xBF80u : 0u);
    bt[(size_t)co * KTOT + ks * 64 + (ci ^ ((co & 7) << 3))] = s;
}

__global__ __launch_bounds__(NTHREADS, 2)
void bconv_kernel(const float* __restrict__ x,
                  const unsigned short* __restrict__ bt,
                  const float* __restrict__ bias,
                  float* __restrict__ out) {
    __shared__ __bf16 Al[BM][BK];   // 16 KB (write-side XOR swizzled)
    __shared__ __bf16 Bl[BN][BK];   // 32 KB (bt pre-swizzled, linear writes)

    const int tid  = threadIdx.x;
    const int lane = tid & 63;
    const int wid  = tid >> 6;

    // XCD-aware bijective swizzle: 784 = 8 * 98
    const int bid = blockIdx.x;
    const int swz = (bid & 7) * (MTOT / BM / 8) + (bid >> 3);
    const int m_base = swz * BM;

    // 8 waves: 2M x 4N, wave tile 64x64
    const int wm = (wid & 1) * 64;
    const int wn = (wid >> 1) * 64;

    // --- A: this thread owns rows r_i = i*64 + (tid>>3), chunk cg = tid&7 ---
    const int cg = tid & 7;
    int aH[2], aW[2];
    long aOff[2];
    char* aDst[2];
#pragma unroll
    for (int i = 0; i < 2; ++i) {
        int r = i * 64 + (tid >> 3);
        int flat = m_base + r;
        aW[i] = flat % WW;
        aH[i] = (flat / WW) % HH;
        aOff[i] = (long)flat * (CIN * 4) + cg * 32;          // fp32 bytes
        aDst[i] = (char*)&Al[0][0] + r * 128 + ((cg * 16) ^ ((r & 7) << 4));
    }

    // --- B: 4 chunks; row co_i = wid*32 + i*8 + (lane>>3), chunk lane&7 ---
    long  bOff[4];
    char* bDst[4];
#pragma unroll
    for (int i = 0; i < 4; ++i) {
        int co = wid * 32 + i * 8 + (lane >> 3);
        bOff[i] = (long)co * (KTOT * 2) + (long)(lane & 7) * 16;
        bDst[i] = (char*)&Bl[0][0] + co * 128 + (lane & 7) * 16;
    }

    f32x4 acc[4][4];
#pragma unroll
    for (int i = 0; i < 4; ++i)
#pragma unroll
        for (int j = 0; j < 4; ++j)
            acc[i][j] = (f32x4){0.f, 0.f, 0.f, 0.f};

    const char* xB  = (const char*)x;
    const char* btB = (const char*)bt;

    // prefetch registers (tile t+1 in flight while computing tile t)
    f32x4 aP[2][2];   // 2 rows x 8 fp32
    f32x4 bP[4];      // 4 x 16B of bf16 bits

    auto LOADS = [&](int ks) {
        const int c   = ks / 9;
        const int tap = ks - c * 9;
        const int dh  = tap / 3 - 1;
        const int dw  = tap % 3 - 1;
        const long soff = (long)(dh * WW + dw) * (CIN * 4) + c * 256;
#pragma unroll
        for (int i = 0; i < 2; ++i) {
            int ih = aH[i] + dh, iw = aW[i] + dw;
            if (((unsigned)ih < (unsigned)HH) && ((unsigned)iw < (unsigned)WW)) {
                const char* gp = xB + aOff[i] + soff;
                aP[i][0] = ((const f32x4*)gp)[0];
                aP[i][1] = ((const f32x4*)gp)[1];
            } else {
                aP[i][0] = (f32x4){0.f, 0.f, 0.f, 0.f};
                aP[i][1] = (f32x4){0.f, 0.f, 0.f, 0.f};
            }
        }
#pragma unroll
        for (int i = 0; i < 4; ++i)
            bP[i] = *(const f32x4*)(btB + bOff[i] + (long)ks * 128);
    };

    LOADS(0);   // prologue: tile 0 loads in flight

    const int swzr = (lane & 7) << 4;
    const int rsel = lane & 15;
    const int csel = (lane >> 4) * 16;

    for (int t = 0; t < NSTEPS; ++t) {
        asm volatile("s_waitcnt vmcnt(0)" ::: "memory");   // tile-t loads arrived

        // fp32 -> bf16 convert (VALU, overlaps other waves' MFMA)
        bf16x8 av[2];
#pragma unroll
        for (int i = 0; i < 2; ++i) {
            av[i][0] = (__bf16)aP[i][0][0]; av[i][1] = (__bf16)aP[i][0][1];
            av[i][2] = (__bf16)aP[i][0][2]; av[i][3] = (__bf16)aP[i][0][3];
            av[i][4] = (__bf16)aP[i][1][0]; av[i][5] = (__bf16)aP[i][1][1];
            av[i][6] = (__bf16)aP[i][1][2]; av[i][7] = (__bf16)aP[i][1][3];
        }

        __builtin_amdgcn_s_barrier();     // all waves done READING tile t-1
        asm volatile("" ::: "memory");

        // stage tile t: reg -> LDS (A write-side XOR; B linear, bt pre-swizzled)
#pragma unroll
        for (int i = 0; i < 2; ++i)
            *(bf16x8*)aDst[i] = av[i];
#pragma unroll
        for (int i = 0; i < 4; ++i)
            *(f32x4*)bDst[i] = bP[i];

        asm volatile("s_waitcnt lgkmcnt(0)" ::: "memory");
        __builtin_amdgcn_s_barrier();     // tile t visible to all waves
        asm volatile("" ::: "memory");

        if (t + 1 < NSTEPS) LOADS(t + 1); // issue next tile's loads (no wait)

        // --- compute tile t: 2 k-chunks of 32, 16 MFMAs each (R2-proven) ---
        const char* Ab = (const char*)&Al[0][0];
        const char* Bb = (const char*)&Bl[0][0];
#pragma unroll
        for (int kk = 0; kk < 2; ++kk) {
            const int colb = kk * 64 + csel;
            bf16x8 af[4], bfr[4];
#pragma unroll
            for (int mi = 0; mi < 4; ++mi)
                af[mi] = *(const bf16x8*)(Ab + (wm + mi * 16 + rsel) * 128 + (colb ^ swzr));
#pragma unroll
            for (int ni = 0; ni < 4; ++ni)
                bfr[ni] = *(const bf16x8*)(Bb + (wn + ni * 16 + rsel) * 128 + (colb ^ swzr));

            __builtin_amdgcn_s_setprio(1);
#pragma unroll
            for (int mi = 0; mi < 4; ++mi)
#pragma unroll
                for (int ni = 0; ni < 4; ++ni)
                    acc[mi][ni] = __builtin_amdgcn_mfma_f32_16x16x32_bf16(
                        af[mi], bfr[ni], acc[mi][ni], 0, 0, 0);
            __builtin_amdgcn_s_setprio(0);
        }
    }

    // --- epilogue: bias + ReLU.  C/D layout: col = lane&15, row = (lane>>4)*4 + j
    const int col_l  = lane & 15;
    const int row_g4 = (lane >> 4) * 4;
#pragma unroll
    for (int ni = 0; ni < 4; ++ni) {
        const int cout = wn + ni * 16 + col_l;
        const float bv = bias[cout];
#pragma unroll
        for (int mi = 0; mi < 4; ++mi) {
            const int row = m_base + wm + mi * 16 + row_g4;
#pragma unroll
            for (int j = 0; j < 4; ++j) {
                float v = acc[mi][ni][j] + bv;
                out[(size_t)(row + j) * COUT + cout] = v > 0.f ? v : 0.f;
            }
        }
    }
}

extern "C" void kernel_launch(void* const* d_in, const int* in_sizes, int n_in,
                              void* d_out, int out_size, void* d_ws, size_t ws_size,
                              hipStream_t stream) {
    const float* x = (const float*)d_in[0];   // (32,56,56,256) fp32
    const float* W = (const float*)d_in[1];   // (3,3,256,256) fp32
    const float* b = (const float*)d_in[2];   // (256,) fp32
    float* out = (float*)d_out;

    unsigned short* bt = (unsigned short*)d_ws;   // 1.18 MB, fits any ws

    binarize_w_kernel<<<dim3(KTOT), dim3(COUT), 0, stream>>>(W, bt);
    bconv_kernel<<<dim3(MTOT / BM), dim3(NTHREADS), 0, stream>>>(x, bt, b, out);
}

// Round 9
// 163.626 us; speedup vs baseline: 1.2239x; 1.2239x over previous
//
#include <hip/hip_runtime.h>
#include <hip/hip_bf16.h>

#define CIN   256
#define COUT  256
#define HH    56
#define WW    56
#define NB    32
#define KTOT  2304            // 3*3*256
#define MTOT  (NB * HH * WW)  // 100352

// ---- 8-phase m201-style geometry: 256x256 tile, 8 waves (128x64 each, 2Mx4N),
//      BK=64 as 2 kk-halves; LDS = 2 bufs x 4 regions [256][32] = 128 KB. ----
#define BM 256
#define BN 256
#define NTHREADS 512
#define NT 36                 // K-tiles of 64 = 4 cin-chunks(64) * 9 taps
#define REG_ELEMS (256 * 32)  // 8192 elems = 16 KB per region

#define BT_BYTES  ((size_t)COUT * KTOT * 2)   // 1,179,648
#define XB_OFF    BT_BYTES
#define XB_BYTES  ((size_t)MTOT * CIN * 2)    // 51,380,224
#define ZB_OFF    (XB_OFF + XB_BYTES)
#define WS_NEEDED (ZB_OFF + 64)

typedef __attribute__((ext_vector_type(4))) float  f32x4;
typedef __attribute__((ext_vector_type(8))) __bf16 bf16x8;

__device__ __forceinline__ void gload_lds16(const void* g, void* l) {
    __builtin_amdgcn_global_load_lds(
        (const __attribute__((address_space(1))) void*)g,
        (__attribute__((address_space(3))) void*)l,
        16, 0, 0);
}

// ---- x fp32 -> bf16 cast (and zero-page init) ----
__global__ void xcast_kernel(const float* __restrict__ x, __bf16* __restrict__ xb,
                             float* __restrict__ zbuf) {
    const size_t total = (size_t)MTOT * CIN / 8;
    size_t idx = (size_t)blockIdx.x * blockDim.x + threadIdx.x;
    const size_t stride = (size_t)gridDim.x * blockDim.x;
    for (size_t g = idx; g < total; g += stride) {
        f32x4 v0 = ((const f32x4*)x)[2 * g];
        f32x4 v1 = ((const f32x4*)x)[2 * g + 1];
        bf16x8 o;
        o[0] = (__bf16)v0[0]; o[1] = (__bf16)v0[1];
        o[2] = (__bf16)v0[2]; o[3] = (__bf16)v0[3];
        o[4] = (__bf16)v1[0]; o[5] = (__bf16)v1[1];
        o[6] = (__bf16)v1[2]; o[7] = (__bf16)v1[3];
        ((bf16x8*)xb)[g] = o;
    }
    if (blockIdx.x == 0 && threadIdx.x < 16) zbuf[threadIdx.x] = 0.f;
}

// ---- binarize W -> bt[cout][ks32*32 + swz(ci)] bf16 {+-1,0} (R4/R5-proven) ----
// ks32 = cin_chunk32 * 9 + tap. Pre-swizzle: ci ^ (((co>>1)&3)<<3), ci in [0,32).
__global__ void binarize_w_kernel(const float* __restrict__ W,
                                  unsigned short* __restrict__ bt) {
    int k  = blockIdx.x;    // tap*256 + cin
    int co = threadIdx.x;
    int tap = k >> 8, cin = k & 255;
    int c2 = cin >> 5, ci = cin & 31;
    int ks = c2 * 9 + tap;
    float w = W[(size_t)k * COUT + co];
    unsigned short s = (w > 0.f) ? 0x3F80u : ((w < 0.f) ? 0xBF80u : 0u);
    bt[(size_t)co * KTOT + ks * 32 + (ci ^ (((co >> 1) & 3) << 3))] = s;
}

__global__ __launch_bounds__(NTHREADS, 2)
void bconv_kernel(const __bf16* __restrict__ xb,
                  const unsigned short* __restrict__ bt,
                  const float* __restrict__ bias,
                  float* __restrict__ out,
                  const char* __restrict__ zb) {
    // [buf][region: 0=A_kk0, 1=A_kk1, 2=B_kk0, 3=B_kk1][256*32]
    __shared__ __bf16 lds[2][4][REG_ELEMS];   // 128 KB

    const int tid  = threadIdx.x;
    const int lane = tid & 63;
    const int wid  = tid >> 6;

    // XCD-aware bijective swizzle: 392 = 8 * 49
    const int bid = blockIdx.x;
    const int swz = (bid & 7) * 49 + (bid >> 3);
    const int m_base = swz * BM;

    // 8 waves: 2M x 4N, wave tile 128x64
    const int wm = (wid >> 2) * 128;
    const int wn = (wid & 3) * 64;

    // --- A staging: 2 issues/half; issue j covers rows j*128 + (tid>>2).
    //     Source chunk pre-swizzle: (tid&3) ^ S(row), S(row)=(row>>1)&3=(tid>>3)&3 ---
    const int schunk = (tid & 3) ^ ((tid >> 3) & 3);
    int aH[2], aW[2];
    long aBase[2];
#pragma unroll
    for (int j = 0; j < 2; ++j) {
        int r = j * 128 + (tid >> 2);
        int flat = m_base + r;
        aW[j] = flat % WW;
        aH[j] = (flat / WW) % HH;
        aBase[j] = (long)flat * (CIN * 2) + schunk * 16;
    }
    // --- B staging: 2 issues/half; issue j covers couts j*128 + (tid>>2) ---
    long bBase[2];
#pragma unroll
    for (int j = 0; j < 2; ++j)
        bBase[j] = (long)(j * 128 + (tid >> 2)) * (KTOT * 2) + (long)(tid & 3) * 16;

    f32x4 acc[8][4];
#pragma unroll
    for (int i = 0; i < 8; ++i)
#pragma unroll
        for (int j = 0; j < 4; ++j)
            acc[i][j] = (f32x4){0.f, 0.f, 0.f, 0.f};

    const char* xbb = (const char*)xb;
    const char* btb = (const char*)bt;

    auto STAGE_A = [&](int ks, int h, int buf) {
        const int c   = ks / 9;
        const int tap = ks - c * 9;
        const int dh  = tap / 3 - 1;
        const int dw  = tap % 3 - 1;
        const long soff = (long)(dh * WW + dw) * (CIN * 2) + c * 128 + h * 64;
#pragma unroll
        for (int j = 0; j < 2; ++j) {
            int ih = aH[j] + dh, iw = aW[j] + dw;
            bool valid = ((unsigned)ih < (unsigned)HH) && ((unsigned)iw < (unsigned)WW);
            const char* g = valid ? (xbb + aBase[j] + soff) : (const char*)zb;
            gload_lds16(g, (char*)&lds[buf][h][0] + j * 8192 + wid * 1024);
        }
    };
    auto STAGE_B = [&](int ks, int h, int buf) {
        const int c   = ks / 9;
        const int tap = ks - c * 9;
        const long soff = (long)(((2 * c + h) * 9 + tap)) * 64;
#pragma unroll
        for (int j = 0; j < 2; ++j)
            gload_lds16(btb + bBase[j] + soff,
                        (char*)&lds[buf][2 + h][0] + j * 8192 + wid * 1024);
    };

    // prologue (issue order fixed for the vmcnt ledger):
    // A0(0),B0(0),A1(0),B1(0),A0(1),B0(1)  -> 12 loads in flight
    STAGE_A(0, 0, 0); STAGE_B(0, 0, 0);
    STAGE_A(0, 1, 0); STAGE_B(0, 1, 0);
    STAGE_A(1, 0, 1); STAGE_B(1, 0, 1);

    // fragment-read geometry (R4/R5-proven, 64-B rows, 0 conflicts):
    // row = base + (lane&15); chunk slot = (lane>>4) ^ ((rsel>>1)&3)
    const int rsel  = lane & 15;
    const int cbyte = ((lane >> 4) ^ ((rsel >> 1) & 3)) * 16;

    bf16x8 bfr[4];
    auto PH = [&](const char* Ar, const char* Br, int mf0, bool readB) {
        if (readB) {
#pragma unroll
            for (int ni = 0; ni < 4; ++ni)
                bfr[ni] = *(const bf16x8*)(Br + (wn + ni * 16 + rsel) * 64 + cbyte);
        }
        bf16x8 af[4];
#pragma unroll
        for (int k = 0; k < 4; ++k)
            af[k] = *(const bf16x8*)(Ar + (wm + (mf0 + k) * 16 + rsel) * 64 + cbyte);
        __builtin_amdgcn_s_setprio(1);
#pragma unroll
        for (int k = 0; k < 4; ++k)
#pragma unroll
            for (int ni = 0; ni < 4; ++ni)
                acc[mf0 + k][ni] = __builtin_amdgcn_mfma_f32_16x16x32_bf16(
                    af[k], bfr[ni], acc[mf0 + k][ni], 0, 0, 0);
        __builtin_amdgcn_s_setprio(0);
    };

    for (int t = 0; t < NT; ++t) {
        const int cur = t & 1;
        // ---- W0: need A0(t),B0(t); 4 newer half-tiles outstanding -> vmcnt(8)
        if (t == NT - 1) { asm volatile("s_waitcnt vmcnt(4)" ::: "memory"); }
        else             { asm volatile("s_waitcnt vmcnt(8)" ::: "memory"); }
        __builtin_amdgcn_s_barrier();
        asm volatile("" ::: "memory");

        const char* A0r = (const char*)&lds[cur][0][0];
        const char* A1r = (const char*)&lds[cur][1][0];
        const char* B0r = (const char*)&lds[cur][2][0];
        const char* B1r = (const char*)&lds[cur][3][0];

        // ph0: stage A1(t+1) -> other buf, compute kk0 m0-3
        if (t + 1 < NT) STAGE_A(t + 1, 1, cur ^ 1);
        PH(A0r, B0r, 0, true);
        // ph1: stage B1(t+1), compute kk0 m4-7
        if (t + 1 < NT) STAGE_B(t + 1, 1, cur ^ 1);
        PH(A0r, B0r, 4, false);

        // ---- W1: need A1(t),B1(t); 4 newer half-tiles outstanding -> vmcnt(8)
        if (t == NT - 1) { asm volatile("s_waitcnt vmcnt(0)" ::: "memory"); }
        else             { asm volatile("s_waitcnt vmcnt(8)" ::: "memory"); }
        __builtin_amdgcn_s_barrier();
        asm volatile("" ::: "memory");

        // ph2: stage A0(t+2) -> CURRENT buf (kk0 regions free after W1), kk1 m0-3
        if (t + 2 < NT) STAGE_A(t + 2, 0, cur);
        PH(A1r, B1r, 0, true);
        // ph3: stage B0(t+2), kk1 m4-7
        if (t + 2 < NT) STAGE_B(t + 2, 0, cur);
        PH(A1r, B1r, 4, false);
    }

    // --- epilogue: bias + ReLU.  C/D layout: col = lane&15, row = (lane>>4)*4 + j
    const int col_l  = lane & 15;
    const int row_g4 = (lane >> 4) * 4;
#pragma unroll
    for (int ni = 0; ni < 4; ++ni) {
        const int cout = wn + ni * 16 + col_l;
        const float bv = bias[cout];
#pragma unroll
        for (int mi = 0; mi < 8; ++mi) {
            const int row = m_base + wm + mi * 16 + row_g4;
#pragma unroll
            for (int j = 0; j < 4; ++j) {
                float v = acc[mi][ni][j] + bv;
                out[(size_t)(row + j) * COUT + cout] = v > 0.f ? v : 0.f;
            }
        }
    }
}

// ================= fallback path (ws too small): round-2 fallback, verbatim ====
__global__ void binarize_w_old_kernel(const float* __restrict__ W,
                                      unsigned short* __restrict__ bt) {
    int k  = blockIdx.x;    // tap*256 + cin
    int co = threadIdx.x;
    int tap = k >> 8, cin = k & 255;
    int c = cin >> 6, ci = cin & 63;
    int ks = c * 9 + tap;
    float w = W[(size_t)k * COUT + co];
    unsigned short s = (w > 0.f) ? 0x3F80u : ((w < 0.f) ? 0xBF80u : 0u);
    bt[(size_t)co * KTOT + ks * 64 + (ci ^ ((co & 7) << 3))] = s;
}

__global__ __launch_bounds__(512, 4)
void bconv_old_kernel(const float* __restrict__ x,
                      const unsigned short* __restrict__ bt,
                      const float* __restrict__ bias,
                      float* __restrict__ out) {
    __shared__ __bf16 Al[128][64];
    __shared__ __bf16 Bl[256][64];

    const int tid  = threadIdx.x;
    const int lane = tid & 63;
    const int wid  = tid >> 6;

    const int bid = blockIdx.x;
    const int swz = (bid & 7) * (MTOT / 128 / 8) + (bid >> 3);
    const int m_base = swz * 128;

    const int wm = (wid & 1) * 64;
    const int wn = (wid >> 1) * 64;

    const int  rB0 = wid * 32 + (lane >> 3);
    const long bB0 = (long)rB0 * (KTOT * 2) + (lane & 7) * 16;

    int aH[2], aW[2], aOff[2];
#pragma unroll
    for (int i = 0; i < 2; ++i) {
        int r = i * 64 + (tid >> 3);
        int flat = m_base + r;
        aW[i] = flat % WW;
        aH[i] = (flat / WW) % HH;
        aOff[i] = flat * (CIN * 4);
    }

    f32x4 acc[4][4];
#pragma unroll
    for (int i = 0; i < 4; ++i)
#pragma unroll
        for (int j = 0; j < 4; ++j)
            acc[i][j] = (f32x4){0.f, 0.f, 0.f, 0.f};

    const char* xfb = (const char*)x;
    const char* btb = (const char*)bt;

    for (int ks = 0; ks < 36; ++ks) {
        const int c    = ks / 9;
        const int tap  = ks % 9;
        const int dh   = tap / 3 - 1;
        const int dw   = tap % 3 - 1;
        const int doff = dh * WW + dw;

        __syncthreads();

#pragma unroll
        for (int i = 0; i < 4; ++i) {
            const char* g = btb + bB0 + (long)i * 8 * (KTOT * 2) + ks * 128;
            gload_lds16(g, &Bl[wid * 32 + i * 8][0]);
        }

        const int cg = tid & 7;
#pragma unroll
        for (int i = 0; i < 2; ++i) {
            int ih = aH[i] + dh, iw = aW[i] + dw;
            f32x4 v0 = (f32x4){0.f, 0.f, 0.f, 0.f};
            f32x4 v1 = (f32x4){0.f, 0.f, 0.f, 0.f};
            if (((unsigned)ih < (unsigned)HH) && ((unsigned)iw < (unsigned)WW)) {
                const float* gp = (const float*)(xfb +
                    (long)(aOff[i] + doff * (CIN * 4) + c * 256 + cg * 32));
                v0 = ((const f32x4*)gp)[0];
                v1 = ((const f32x4*)gp)[1];
            }
            bf16x8 o;
            o[0] = (__bf16)v0[0]; o[1] = (__bf16)v0[1];
            o[2] = (__bf16)v0[2]; o[3] = (__bf16)v0[3];
            o[4] = (__bf16)v1[0]; o[5] = (__bf16)v1[1];
            o[6] = (__bf16)v1[2]; o[7] = (__bf16)v1[3];
            int r = i * 64 + (tid >> 3);
            *(bf16x8*)((char*)&Al[0][0] + r * 128 + ((cg * 16) ^ ((r & 7) << 4))) = o;
        }

        __syncthreads();

        const char* Ab = (const char*)&Al[0][0];
        const char* Bb = (const char*)&Bl[0][0];
        const int swzr = (lane & 7) << 4;
        const int rsel = lane & 15;
        const int csel = (lane >> 4) * 16;
#pragma unroll
        for (int kk = 0; kk < 2; ++kk) {
            const int colb = kk * 64 + csel;
            bf16x8 af[4], bfr[4];
#pragma unroll
            for (int mi = 0; mi < 4; ++mi)
                af[mi] = *(const bf16x8*)(Ab + (wm + mi * 16 + rsel) * 128 + (colb ^ swzr));
#pragma unroll
            for (int ni = 0; ni < 4; ++ni)
                bfr[ni] = *(const bf16x8*)(Bb + (wn + ni * 16 + rsel) * 128 + (colb ^ swzr));
#pragma unroll
            for (int mi = 0; mi < 4; ++mi)
#pragma unroll
                for (int ni = 0; ni < 4; ++ni)
                    acc[mi][ni] = __builtin_amdgcn_mfma_f32_16x16x32_bf16(
                        af[mi], bfr[ni], acc[mi][ni], 0, 0, 0);
        }
    }

    const int col_l  = lane & 15;
    const int row_g4 = (lane >> 4) * 4;
#pragma unroll
    for (int ni = 0; ni < 4; ++ni) {
        const int cout = wn + ni * 16 + col_l;
        const float bv = bias[cout];
#pragma unroll
        for (int mi = 0; mi < 4; ++mi) {
            const int row = m_base + wm + mi * 16 + row_g4;
#pragma unroll
            for (int j = 0; j < 4; ++j) {
                float v = acc[mi][ni][j] + bv;
                out[(size_t)(row + j) * COUT + cout] = v > 0.f ? v : 0.f;
            }
        }
    }
}

extern "C" void kernel_launch(void* const* d_in, const int* in_sizes, int n_in,
                              void* d_out, int out_size, void* d_ws, size_t ws_size,
                              hipStream_t stream) {
    const float* x = (const float*)d_in[0];   // (32,56,56,256) fp32
    const float* W = (const float*)d_in[1];   // (3,3,256,256) fp32
    const float* b = (const float*)d_in[2];   // (256,) fp32
    float* out = (float*)d_out;

    char* ws = (char*)d_ws;
    unsigned short* bt = (unsigned short*)ws;
    __bf16* xb   = (__bf16*)(ws + XB_OFF);
    float*  zbuf = (float*)(ws + ZB_OFF);

    if (ws_size >= WS_NEEDED) {
        binarize_w_kernel<<<dim3(KTOT), dim3(COUT), 0, stream>>>(W, bt);
        xcast_kernel<<<dim3(2048), dim3(256), 0, stream>>>(x, xb, zbuf);
        bconv_kernel<<<dim3(MTOT / BM), dim3(NTHREADS), 0, stream>>>(
            xb, bt, b, out, (const char*)zbuf);
    } else {
        binarize_w_old_kernel<<<dim3(KTOT), dim3(COUT), 0, stream>>>(W, bt);
        bconv_old_kernel<<<dim3(MTOT / 128), dim3(512), 0, stream>>>(x, bt, b, out);
    }
}

// Round 10
// 162.177 us; speedup vs baseline: 1.2348x; 1.0089x over previous
//
#include <hip/hip_runtime.h>
#include <hip/hip_bf16.h>

#define CIN   256
#define COUT  256
#define HH    56
#define WW    56
#define NB    32
#define KTOT  2304            // 3*3*256
#define MTOT  (NB * HH * WW)  // 100352

// ---- geometry: 128x256 tile, 8 waves (64x64 each, 2Mx4N), BK=32,
//      DOUBLE-buffered LDS (2 x 24 KB), ONE syncthreads per step,
//      stage issued a full step before its drain. ----
#define BM 128
#define BN 256
#define BK 32
#define NTHREADS 512
#define NSTEPS (KTOT / BK)               // 72 = 8 cin-chunks(32) * 9 taps
#define SLOT_ELEMS (BM * BK + BN * BK)   // 12288 elems = 24 KB per slot

#define BT_BYTES  ((size_t)COUT * KTOT * 2)   // 1,179,648
#define XB_OFF    BT_BYTES
#define XB_BYTES  ((size_t)MTOT * CIN * 2)    // 51,380,224
#define ZB_OFF    (XB_OFF + XB_BYTES)
#define WS_NEEDED (ZB_OFF + 64)

typedef __attribute__((ext_vector_type(4))) float  f32x4;
typedef __attribute__((ext_vector_type(8))) __bf16 bf16x8;

__device__ __forceinline__ void gload_lds16(const void* g, void* l) {
    __builtin_amdgcn_global_load_lds(
        (const __attribute__((address_space(1))) void*)g,
        (__attribute__((address_space(3))) void*)l,
        16, 0, 0);
}

// ---- x fp32 -> bf16 cast (and zero-page init) ----
__global__ void xcast_kernel(const float* __restrict__ x, __bf16* __restrict__ xb,
                             float* __restrict__ zbuf) {
    const size_t total = (size_t)MTOT * CIN / 8;
    size_t idx = (size_t)blockIdx.x * blockDim.x + threadIdx.x;
    const size_t stride = (size_t)gridDim.x * blockDim.x;
    for (size_t g = idx; g < total; g += stride) {
        f32x4 v0 = ((const f32x4*)x)[2 * g];
        f32x4 v1 = ((const f32x4*)x)[2 * g + 1];
        bf16x8 o;
        o[0] = (__bf16)v0[0]; o[1] = (__bf16)v0[1];
        o[2] = (__bf16)v0[2]; o[3] = (__bf16)v0[3];
        o[4] = (__bf16)v1[0]; o[5] = (__bf16)v1[1];
        o[6] = (__bf16)v1[2]; o[7] = (__bf16)v1[3];
        ((bf16x8*)xb)[g] = o;
    }
    if (blockIdx.x == 0 && threadIdx.x < 16) zbuf[threadIdx.x] = 0.f;
}

// ---- binarize W -> bt[cout][ks*32 + swz(ci)] bf16 {+-1,0}; BK=32 layout ----
// ks = cin_chunk32 * 9 + tap (taps innermost). Pre-swizzle: ci ^ (((co>>1)&3)<<3).
// (R4/R5-proven: 0 LDS bank conflicts)
__global__ void binarize_w_kernel(const float* __restrict__ W,
                                  unsigned short* __restrict__ bt) {
    int k  = blockIdx.x;    // tap*256 + cin
    int co = threadIdx.x;
    int tap = k >> 8, cin = k & 255;
    int c2 = cin >> 5, ci = cin & 31;
    int ks = c2 * 9 + tap;
    float w = W[(size_t)k * COUT + co];
    unsigned short s = (w > 0.f) ? 0x3F80u : ((w < 0.f) ? 0xBF80u : 0u);
    bt[(size_t)co * KTOT + ks * 32 + (ci ^ (((co >> 1) & 3) << 3))] = s;
}

__global__ __launch_bounds__(NTHREADS, 4)
void bconv_kernel(const __bf16* __restrict__ xb,
                  const unsigned short* __restrict__ bt,
                  const float* __restrict__ bias,
                  float* __restrict__ out,
                  const char* __restrict__ zb) {
    __shared__ __bf16 lds[2 * SLOT_ELEMS];   // 48 KB -> 2 blocks/CU (VGPR-bound)

    const int tid  = threadIdx.x;
    const int lane = tid & 63;
    const int wid  = tid >> 6;

    // XCD-aware bijective swizzle: 784 = 8 * 98
    const int bid = blockIdx.x;
    const int swz = (bid & 7) * (MTOT / BM / 8) + (bid >> 3);
    const int m_base = swz * BM;

    // 8 waves: 2M x 4N, wave tile 64x64
    const int wm = (wid >> 2) * 64;
    const int wn = (wid & 3) * 64;

    // --- B staging (R5 verbatim): 2 loads/thread; load j: cout = j*128 + (tid>>2) ---
    long bSrc[2];
#pragma unroll
    for (int j = 0; j < 2; ++j) {
        int co = j * 128 + (tid >> 2);
        bSrc[j] = (long)co * (KTOT * 2) + (long)(tid & 3) * 16;
    }

    // --- A staging (R5 verbatim): 1 load/thread; row = tid>>2, chunk pre-swizzled:
    //     chunk' = (tid&3) ^ S(row), S(row) = (row>>1)&3 = (tid>>3)&3 ---
    const int schunk = (tid & 3) ^ ((tid >> 3) & 3);
    int aHH, aWW;
    long aBase;
    {
        int r = tid >> 2;                 // 0..127
        int flat = m_base + r;
        aWW = flat % WW;
        aHH = (flat / WW) % HH;
        aBase = (long)flat * (CIN * 2) + schunk * 16;
    }

    f32x4 acc[4][4];
#pragma unroll
    for (int i = 0; i < 4; ++i)
#pragma unroll
        for (int j = 0; j < 4; ++j)
            acc[i][j] = (f32x4){0.f, 0.f, 0.f, 0.f};

    const char* xbb = (const char*)xb;
    const char* btb = (const char*)bt;

    auto STAGE = [&](int ks, int slot) {
        __bf16* As = &lds[slot * SLOT_ELEMS];
        __bf16* Bs = As + BM * BK;
#pragma unroll
        for (int j = 0; j < 2; ++j)
            gload_lds16(btb + bSrc[j] + (long)ks * 64,
                        &Bs[(j * 128 + wid * 16) * BK]);
        const int c2  = ks / 9;
        const int tap = ks - c2 * 9;
        const int dh  = tap / 3 - 1;
        const int dw  = tap % 3 - 1;
        int ih = aHH + dh, iw = aWW + dw;
        bool valid = ((unsigned)ih < (unsigned)HH) && ((unsigned)iw < (unsigned)WW);
        const char* g = valid
            ? (xbb + aBase + (long)(dh * WW + dw) * (CIN * 2) + c2 * 64)
            : (const char*)zb;
        gload_lds16(g, &As[(wid * 16) * BK]);
    };

    // prologue: stage tile 0 into buf 0, publish it
    STAGE(0, 0);
    __syncthreads();

    // fragment-read geometry (R4/R5-proven, 64-B rows, 0 conflicts):
    // row = base + (lane&15); chunk slot = (lane>>4) ^ ((rsel>>1)&3)
    const int rsel  = lane & 15;
    const int cbyte = ((lane >> 4) ^ ((rsel >> 1) & 3)) * 16;

    for (int t = 0; t < NSTEPS; ++t) {
        const int cur = t & 1;
        // issue next tile's staging into the other buffer (drained at the sync
        // BELOW, after a full compute phase of latency hiding)
        if (t + 1 < NSTEPS) STAGE(t + 1, cur ^ 1);

        const char* As = (const char*)&lds[cur * SLOT_ELEMS];
        const char* Bs = As + BM * BK * 2;

        bf16x8 af[4], bfr[4];
#pragma unroll
        for (int ni = 0; ni < 4; ++ni)
            bfr[ni] = *(const bf16x8*)(Bs + (wn + ni * 16 + rsel) * (BK * 2) + cbyte);
#pragma unroll
        for (int mi = 0; mi < 4; ++mi)
            af[mi] = *(const bf16x8*)(As + (wm + mi * 16 + rsel) * (BK * 2) + cbyte);

#pragma unroll
        for (int mi = 0; mi < 4; ++mi)
#pragma unroll
            for (int ni = 0; ni < 4; ++ni)
                acc[mi][ni] = __builtin_amdgcn_mfma_f32_16x16x32_bf16(
                    af[mi], bfr[ni], acc[mi][ni], 0, 0, 0);

        // one barrier per step: drains vmcnt (publishes tile t+1 in buf^1),
        // and all waves' reads of buf cur are done -> iter t+1 may overwrite it
        __syncthreads();
    }

    // --- epilogue: bias + ReLU.  C/D layout: col = lane&15, row = (lane>>4)*4 + j
    const int col_l  = lane & 15;
    const int row_g4 = (lane >> 4) * 4;
#pragma unroll
    for (int ni = 0; ni < 4; ++ni) {
        const int cout = wn + ni * 16 + col_l;
        const float bv = bias[cout];
#pragma unroll
        for (int mi = 0; mi < 4; ++mi) {
            const int row = m_base + wm + mi * 16 + row_g4;
#pragma unroll
            for (int j = 0; j < 4; ++j) {
                float v = acc[mi][ni][j] + bv;
                out[(size_t)(row + j) * COUT + cout] = v > 0.f ? v : 0.f;
            }
        }
    }
}

// ================= fallback path (ws too small): round-2 fallback, verbatim ====
__global__ void binarize_w_old_kernel(const float* __restrict__ W,
                                      unsigned short* __restrict__ bt) {
    int k  = blockIdx.x;    // tap*256 + cin
    int co = threadIdx.x;
    int tap = k >> 8, cin = k & 255;
    int c = cin >> 6, ci = cin & 63;
    int ks = c * 9 + tap;
    float w = W[(size_t)k * COUT + co];
    unsigned short s = (w > 0.f) ? 0x3F80u : ((w < 0.f) ? 0xBF80u : 0u);
    bt[(size_t)co * KTOT + ks * 64 + (ci ^ ((co & 7) << 3))] = s;
}

__global__ __launch_bounds__(512, 4)
void bconv_old_kernel(const float* __restrict__ x,
                      const unsigned short* __restrict__ bt,
                      const float* __restrict__ bias,
                      float* __restrict__ out) {
    __shared__ __bf16 Al[128][64];
    __shared__ __bf16 Bl[256][64];

    const int tid  = threadIdx.x;
    const int lane = tid & 63;
    const int wid  = tid >> 6;

    const int bid = blockIdx.x;
    const int swz = (bid & 7) * (MTOT / 128 / 8) + (bid >> 3);
    const int m_base = swz * 128;

    const int wm = (wid & 1) * 64;
    const int wn = (wid >> 1) * 64;

    const int  rB0 = wid * 32 + (lane >> 3);
    const long bB0 = (long)rB0 * (KTOT * 2) + (lane & 7) * 16;

    int aH[2], aW[2], aOff[2];
#pragma unroll
    for (int i = 0; i < 2; ++i) {
        int r = i * 64 + (tid >> 3);
        int flat = m_base + r;
        aW[i] = flat % WW;
        aH[i] = (flat / WW) % HH;
        aOff[i] = flat * (CIN * 4);
    }

    f32x4 acc[4][4];
#pragma unroll
    for (int i = 0; i < 4; ++i)
#pragma unroll
        for (int j = 0; j < 4; ++j)
            acc[i][j] = (f32x4){0.f, 0.f, 0.f, 0.f};

    const char* xfb = (const char*)x;
    const char* btb = (const char*)bt;

    for (int ks = 0; ks < 36; ++ks) {
        const int c    = ks / 9;
        const int tap  = ks % 9;
        const int dh   = tap / 3 - 1;
        const int dw   = tap % 3 - 1;
        const int doff = dh * WW + dw;

        __syncthreads();

#pragma unroll
        for (int i = 0; i < 4; ++i) {
            const char* g = btb + bB0 + (long)i * 8 * (KTOT * 2) + ks * 128;
            gload_lds16(g, &Bl[wid * 32 + i * 8][0]);
        }

        const int cg = tid & 7;
#pragma unroll
        for (int i = 0; i < 2; ++i) {
            int ih = aH[i] + dh, iw = aW[i] + dw;
            f32x4 v0 = (f32x4){0.f, 0.f, 0.f, 0.f};
            f32x4 v1 = (f32x4){0.f, 0.f, 0.f, 0.f};
            if (((unsigned)ih < (unsigned)HH) && ((unsigned)iw < (unsigned)WW)) {
                const float* gp = (const float*)(xfb +
                    (long)(aOff[i] + doff * (CIN * 4) + c * 256 + cg * 32));
                v0 = ((const f32x4*)gp)[0];
                v1 = ((const f32x4*)gp)[1];
            }
            bf16x8 o;
            o[0] = (__bf16)v0[0]; o[1] = (__bf16)v0[1];
            o[2] = (__bf16)v0[2]; o[3] = (__bf16)v0[3];
            o[4] = (__bf16)v1[0]; o[5] = (__bf16)v1[1];
            o[6] = (__bf16)v1[2]; o[7] = (__bf16)v1[3];
            int r = i * 64 + (tid >> 3);
            *(bf16x8*)((char*)&Al[0][0] + r * 128 + ((cg * 16) ^ ((r & 7) << 4))) = o;
        }

        __syncthreads();

        const char* Ab = (const char*)&Al[0][0];
        const char* Bb = (const char*)&Bl[0][0];
        const int swzr = (lane & 7) << 4;
        const int rsel = lane & 15;
        const int csel = (lane >> 4) * 16;
#pragma unroll
        for (int kk = 0; kk < 2; ++kk) {
            const int colb = kk * 64 + csel;
            bf16x8 af[4], bfr[4];
#pragma unroll
            for (int mi = 0; mi < 4; ++mi)
                af[mi] = *(const bf16x8*)(Ab + (wm + mi * 16 + rsel) * 128 + (colb ^ swzr));
#pragma unroll
            for (int ni = 0; ni < 4; ++ni)
                bfr[ni] = *(const bf16x8*)(Bb + (wn + ni * 16 + rsel) * 128 + (colb ^ swzr));
#pragma unroll
            for (int mi = 0; mi < 4; ++mi)
#pragma unroll
                for (int ni = 0; ni < 4; ++ni)
                    acc[mi][ni] = __builtin_amdgcn_mfma_f32_16x16x32_bf16(
                        af[mi], bfr[ni], acc[mi][ni], 0, 0, 0);
        }
    }

    const int col_l  = lane & 15;
    const int row_g4 = (lane >> 4) * 4;
#pragma unroll
    for (int ni = 0; ni < 4; ++ni) {
        const int cout = wn + ni * 16 + col_l;
        const float bv = bias[cout];
#pragma unroll
        for (int mi = 0; mi < 4; ++mi) {
            const int row = m_base + wm + mi * 16 + row_g4;
#pragma unroll
            for (int j = 0; j < 4; ++j) {
                float v = acc[mi][ni][j] + bv;
                out[(size_t)(row + j) * COUT + cout] = v > 0.f ? v : 0.f;
            }
        }
    }
}

extern "C" void kernel_launch(void* const* d_in, const int* in_sizes, int n_in,
                              void* d_out, int out_size, void* d_ws, size_t ws_size,
                              hipStream_t stream) {
    const float* x = (const float*)d_in[0];   // (32,56,56,256) fp32
    const float* W = (const float*)d_in[1];   // (3,3,256,256) fp32
    const float* b = (const float*)d_in[2];   // (256,) fp32
    float* out = (float*)d_out;

    char* ws = (char*)d_ws;
    unsigned short* bt = (unsigned short*)ws;
    __bf16* xb   = (__bf16*)(ws + XB_OFF);
    float*  zbuf = (float*)(ws + ZB_OFF);

    if (ws_size >= WS_NEEDED) {
        binarize_w_kernel<<<dim3(KTOT), dim3(COUT), 0, stream>>>(W, bt);
        xcast_kernel<<<dim3(2048), dim3(256), 0, stream>>>(x, xb, zbuf);
        bconv_kernel<<<dim3(MTOT / BM), dim3(NTHREADS), 0, stream>>>(
            xb, bt, b, out, (const char*)zbuf);
    } else {
        binarize_w_old_kernel<<<dim3(KTOT), dim3(COUT), 0, stream>>>(W, bt);
        bconv_old_kernel<<<dim3(MTOT / 128), dim3(512), 0, stream>>>(x, bt, b, out);
    }
}